// Round 4
// baseline (197.167 us; speedup 1.0000x reference)
//
#include <hip/hip_runtime.h>

#define IN_DIM 128
#define NCOL   256          // UV row: [U(128) | V(128)], bf16
#define TPITCH (NCOL + 8)   // LDS tile pitch in bf16 (528 B, 16B-aligned, breaks pow2)

typedef __bf16 bfx8 __attribute__((ext_vector_type(8)));
typedef float  f32x4 __attribute__((ext_vector_type(4)));

// ---------------- GEMM: UV = bf16( z @ Weff^T + [b1|0] ) ----------------
// Weff[n][k] = (n<128) ? W1[n][k] : W1[n-128][128+k]  (W1 is [128][256] fp32)
// M=100000, K=128, N=256. MFMA 16x16x32 bf16; B entirely in registers,
// rebuilt per block from the L1/L2-hot 131 KB W1 (no prep kernel).
// Block = 256 threads = 4 waves; wave w owns n-slice [w*64, w*64+64).
// One 32-row m-chunk per block -> grid 3125, max load concurrency.
__global__ __launch_bounds__(256) void gemm_mfma(
    const float* __restrict__ z, const float* __restrict__ W1,
    const float* __restrict__ b1, __bf16* __restrict__ UV, int M)
{
    __shared__ __bf16 tile[32][TPITCH];

    const int tid  = threadIdx.x;
    const int wave = tid >> 6;
    const int lane = tid & 63;
    const int l15  = lane & 15;
    const int q    = lane >> 4;      // quad 0..3
    const int n0   = wave * 64;
    const int m0   = blockIdx.x * 32;   // M % 32 == 0

    // --- A fragments first: long-latency HBM loads, all independent ---
    bfx8 afrag[2][4];
#pragma unroll
    for (int mt = 0; mt < 2; ++mt) {
#pragma unroll
        for (int kk = 0; kk < 4; ++kk) {
            const float* p = z + (size_t)(m0 + mt * 16 + l15) * IN_DIM + kk * 32 + q * 8;
            float4 f0 = *(const float4*)p;
            float4 f1 = *(const float4*)(p + 4);
            bfx8 a;
            a[0] = (__bf16)f0.x; a[1] = (__bf16)f0.y; a[2] = (__bf16)f0.z; a[3] = (__bf16)f0.w;
            a[4] = (__bf16)f1.x; a[5] = (__bf16)f1.y; a[6] = (__bf16)f1.z; a[7] = (__bf16)f1.w;
            afrag[mt][kk] = a;
        }
    }

    // --- B fragments from fp32 W1 (L1/L2-hot): lane holds Weff[n][kk*32+q*8 ..+8] ---
    bfx8  bfrag[4][4];
    float bias[4];
#pragma unroll
    for (int nt = 0; nt < 4; ++nt) {
        const int n = n0 + nt * 16 + l15;
        bias[nt] = (n < 128) ? b1[n] : 0.f;
#pragma unroll
        for (int kk = 0; kk < 4; ++kk) {
            const int k = kk * 32 + q * 8;
            const float* p = (n < 128) ? (W1 + n * 256 + k)
                                       : (W1 + (n - 128) * 256 + 128 + k);
            float4 f0 = *(const float4*)p;
            float4 f1 = *(const float4*)(p + 4);
            bfx8 b;
            b[0] = (__bf16)f0.x; b[1] = (__bf16)f0.y; b[2] = (__bf16)f0.z; b[3] = (__bf16)f0.w;
            b[4] = (__bf16)f1.x; b[5] = (__bf16)f1.y; b[6] = (__bf16)f1.z; b[7] = (__bf16)f1.w;
            bfrag[nt][kk] = b;
        }
    }

    f32x4 acc[2][4];
#pragma unroll
    for (int mt = 0; mt < 2; ++mt)
#pragma unroll
        for (int nt = 0; nt < 4; ++nt)
            acc[mt][nt] = (f32x4){0.f, 0.f, 0.f, 0.f};

#pragma unroll
    for (int kk = 0; kk < 4; ++kk)
#pragma unroll
        for (int mt = 0; mt < 2; ++mt)
#pragma unroll
            for (int nt = 0; nt < 4; ++nt)
                acc[mt][nt] = __builtin_amdgcn_mfma_f32_16x16x32_bf16(
                    afrag[mt][kk], bfrag[nt][kk], acc[mt][nt], 0, 0, 0);

    // --- epilogue: bias + round to bf16 into LDS tile (D: col=l15, row=q*4+r) ---
#pragma unroll
    for (int mt = 0; mt < 2; ++mt)
#pragma unroll
        for (int nt = 0; nt < 4; ++nt) {
            const int col = n0 + nt * 16 + l15;
#pragma unroll
            for (int r = 0; r < 4; ++r)
                tile[mt * 16 + q * 4 + r][col] = (__bf16)(acc[mt][nt][r] + bias[nt]);
        }
    __syncthreads();

    // --- coalesced store: 32 rows x 512 B, 16 B per thread per pass ---
#pragma unroll
    for (int s = 0; s < 4; ++s) {
        const int lin = s * 256 + tid;      // dwordx4 index in 32x256 tile
        const int row = lin >> 5;
        const int c   = lin & 31;
        bfx8 v = *(const bfx8*)&tile[row][c * 8];
        *(bfx8*)(UV + (size_t)(m0 + row) * NCOL + c * 8) = v;
    }
}

// ---------------- per-edge MLP ----------------
// 16-lane group handles 4 edges (8 independent 16 B gathers in flight/thread).
// lane covers 8 hidden channels; b1 already folded into U.
// h = relu(u+v); out = h . w2 + b2.
__global__ __launch_bounds__(256) void edge_mlp(
    const __bf16* __restrict__ UV, const int* __restrict__ ei,
    const float* __restrict__ W2, const float* __restrict__ b2,
    float* __restrict__ out, int E)
{
    const int gt   = blockIdx.x * blockDim.x + threadIdx.x;
    const int lane = threadIdx.x & 15;
    const int g    = gt >> 4;
    const int e0   = g * 4;
    const int j0   = lane * 8;

    float ww[8];
    {
        float4 w0 = *(const float4*)(W2 + j0);
        float4 w1 = *(const float4*)(W2 + j0 + 4);
        ww[0] = w0.x; ww[1] = w0.y; ww[2] = w0.z; ww[3] = w0.w;
        ww[4] = w1.x; ww[5] = w1.y; ww[6] = w1.z; ww[7] = w1.w;
    }

    if (e0 >= E) return;   // E % 4 == 0

    const int4 s4 = *(const int4*)(ei + e0);       // src of e0..e0+3 (same addr across
    const int4 d4 = *(const int4*)(ei + E + e0);   //  the 16 lanes -> L1 broadcast)

    bfx8 u0 = *(const bfx8*)(UV + (size_t)s4.x * NCOL + j0);
    bfx8 u1 = *(const bfx8*)(UV + (size_t)s4.y * NCOL + j0);
    bfx8 u2 = *(const bfx8*)(UV + (size_t)s4.z * NCOL + j0);
    bfx8 u3 = *(const bfx8*)(UV + (size_t)s4.w * NCOL + j0);
    bfx8 v0 = *(const bfx8*)(UV + (size_t)d4.x * NCOL + 128 + j0);
    bfx8 v1 = *(const bfx8*)(UV + (size_t)d4.y * NCOL + 128 + j0);
    bfx8 v2 = *(const bfx8*)(UV + (size_t)d4.z * NCOL + 128 + j0);
    bfx8 v3 = *(const bfx8*)(UV + (size_t)d4.w * NCOL + 128 + j0);

    float s0 = 0.f, s1 = 0.f, s2 = 0.f, s3 = 0.f;
#pragma unroll
    for (int i = 0; i < 8; ++i) {
        s0 = fmaf(fmaxf((float)u0[i] + (float)v0[i], 0.f), ww[i], s0);
        s1 = fmaf(fmaxf((float)u1[i] + (float)v1[i], 0.f), ww[i], s1);
        s2 = fmaf(fmaxf((float)u2[i] + (float)v2[i], 0.f), ww[i], s2);
        s3 = fmaf(fmaxf((float)u3[i] + (float)v3[i], 0.f), ww[i], s3);
    }

#pragma unroll
    for (int d = 1; d < 16; d <<= 1) {
        s0 += __shfl_xor(s0, d);
        s1 += __shfl_xor(s1, d);
        s2 += __shfl_xor(s2, d);
        s3 += __shfl_xor(s3, d);
    }

    if (lane == 0) {
        const float bb = b2[0];
        *(float4*)(out + e0) = make_float4(s0 + bb, s1 + bb, s2 + bb, s3 + bb);
    }
}

extern "C" void kernel_launch(void* const* d_in, const int* in_sizes, int n_in,
                              void* d_out, int out_size, void* d_ws, size_t ws_size,
                              hipStream_t stream)
{
    const float* z  = (const float*)d_in[0];
    const int*   ei = (const int*)d_in[1];
    const float* W1 = (const float*)d_in[2];
    const float* b1 = (const float*)d_in[3];
    const float* W2 = (const float*)d_in[4];
    const float* b2 = (const float*)d_in[5];
    float* out = (float*)d_out;

    const int M = in_sizes[0] / IN_DIM;   // 100000 nodes
    const int E = in_sizes[1] / 2;        // 600000 edges

    __bf16* UV = (__bf16*)d_ws;           // [M][256] bf16 = 51.2 MB

    gemm_mfma<<<M / 32, 256, 0, stream>>>(z, W1, b1, UV, M);   // 3125 blocks

    const int groups  = (E + 3) / 4;                  // 150000
    const int eblocks = (groups * 16 + 255) / 256;    // 9375
    edge_mlp<<<eblocks, 256, 0, stream>>>(UV, ei, W2, b2, out, E);
}